// Round 3
// baseline (311.965 us; speedup 1.0000x reference)
//
#include <hip/hip_runtime.h>

#define B_SZ 32
#define H_SZ 64
#define W_SZ 64
#define DIM 64
#define K_CODES 512
#define N_VEC (B_SZ * H_SZ * W_SZ)   // 131072
#define VPB 128                       // vectors per block
#define KC 128                        // codes per LDS chunk
#define NCHUNK (K_CODES / KC)         // 4
#define Q_OFF 1
#define PERP_OFF 8388609
#define ENC_OFF 8388610

// ---------------------------------------------------------------------------
// Kernel 0: ||e||^2 per code (512 values) — removes the per-chunk sEE pass
// and one __syncthreads per chunk from the hot kernel.
// ---------------------------------------------------------------------------
__global__ __launch_bounds__(64) void ee_kernel(const float* __restrict__ emb_w,
                                                float* __restrict__ ee)
{
    const int k = blockIdx.x * 64 + threadIdx.x;
    const float4* e4 = reinterpret_cast<const float4*>(emb_w + (size_t)k * DIM);
    float s0 = 0, s1 = 0, s2 = 0, s3 = 0;
#pragma unroll
    for (int d4 = 0; d4 < 16; ++d4) {
        const float4 v = e4[d4];
        s0 = fmaf(v.x, v.x, s0); s1 = fmaf(v.y, v.y, s1);
        s2 = fmaf(v.z, v.z, s2); s3 = fmaf(v.w, v.w, s3);
    }
    ee[k] = (s0 + s1) + (s2 + s3);
}

// ---------------------------------------------------------------------------
// Kernel 1: distance GEMM + argmin, 8x8 register tile (bytes/FMA = 1.0),
// fused with: idx write, counts histogram, FULL one-hot row writes (replaces
// the 268 MB memset — streams overlap compute across blocks), dw segment-sum.
//
// Block: 256 threads = 16 tv x 16 tc; thread tile 8 vec x 8 codes.
// Block tile: 128 vectors x 128-code chunks (4 chunks).
// LDS: sX 32 KB, sE 32 KB (granule-XOR swizzle keyed on row>>3, the bits
// that vary across concurrent readers -> 2-way max aliasing = free).
// Tie rule: ascending-k scan with strict <, cross-thread reduce prefers
// smaller k on equal dist == numpy argmin (first minimum).
// ---------------------------------------------------------------------------
__global__ __launch_bounds__(256) void argmin_scatter_kernel(
    const float* __restrict__ inputs,
    const float* __restrict__ emb_w,
    const float* __restrict__ eeg,
    int* __restrict__ idx,
    float* __restrict__ counts,
    float* __restrict__ dw,
    float* __restrict__ enc)
{
    __shared__ float4 sX[VPB * 16];    // 32 KB
    __shared__ float4 sE[KC * 16];     // 32 KB
    __shared__ int    sBK[VPB];
    float* sRbest = (float*)sE;                    // overlay after chunk loop
    int*   sRk    = ((int*)sE) + VPB * 17;         // stride 17: 4-way max

    const int t  = threadIdx.x;
    const int tv = t & 15;
    const int tc = t >> 4;
    const int v0 = tv * 8;
    const int k0 = tc * 8;
    const size_t vecbase = (size_t)blockIdx.x * VPB;

    // ---- stage X tile (128 vec x 64 d), swizzled granules ----
    {
        const float4* inp4 = reinterpret_cast<const float4*>(inputs + vecbase * DIM);
#pragma unroll
        for (int r = 0; r < 8; ++r) {
            const int g = r * 256 + t;            // = v*16 + d4
            const int v = g >> 4, d4 = g & 15;
            sX[v * 16 + (d4 ^ (v >> 3))] = inp4[g];
        }
    }

    float xx[8], best[8];
    int bestk[8];
#pragma unroll
    for (int i = 0; i < 8; ++i) { xx[i] = 0.f; best[i] = 3.4e38f; bestk[i] = 0; }

    for (int ch = 0; ch < NCHUNK; ++ch) {
        __syncthreads();   // prior chunk's sE reads done (and sX staged, ch==0)
        {
            const float4* eb4 = reinterpret_cast<const float4*>(
                emb_w + (size_t)(ch * KC) * DIM);
#pragma unroll
            for (int r = 0; r < 8; ++r) {
                const int g = r * 256 + t;        // = k*16 + d4
                const int k = g >> 4, d4 = g & 15;
                sE[k * 16 + (d4 ^ (k >> 3))] = eb4[g];
            }
        }
        // preload this thread's 8 ||e||^2 (L2-hot, overlaps with staging)
        float ee[8];
#pragma unroll
        for (int c = 0; c < 8; ++c) ee[c] = eeg[ch * KC + k0 + c];
        __syncthreads();

        float acc[8][8];
#pragma unroll
        for (int i = 0; i < 8; ++i)
#pragma unroll
            for (int c = 0; c < 8; ++c) acc[i][c] = 0.f;

#pragma unroll 4
        for (int d4 = 0; d4 < 16; ++d4) {
            float4 xv[8];
#pragma unroll
            for (int i = 0; i < 8; ++i)
                xv[i] = sX[(v0 + i) * 16 + (d4 ^ tv)];     // (v0+i)>>3 == tv
            if (ch == 0) {                                  // ||x||^2 once
#pragma unroll
                for (int i = 0; i < 8; ++i) {
                    xx[i] = fmaf(xv[i].x, xv[i].x, xx[i]);
                    xx[i] = fmaf(xv[i].y, xv[i].y, xx[i]);
                    xx[i] = fmaf(xv[i].z, xv[i].z, xx[i]);
                    xx[i] = fmaf(xv[i].w, xv[i].w, xx[i]);
                }
            }
#pragma unroll
            for (int c = 0; c < 8; ++c) {
                const float4 ev = sE[(k0 + c) * 16 + (d4 ^ tc)];  // (k0+c)>>3 == tc
#pragma unroll
                for (int i = 0; i < 8; ++i) {
                    acc[i][c] = fmaf(xv[i].x, ev.x, acc[i][c]);
                    acc[i][c] = fmaf(xv[i].y, ev.y, acc[i][c]);
                    acc[i][c] = fmaf(xv[i].z, ev.z, acc[i][c]);
                    acc[i][c] = fmaf(xv[i].w, ev.w, acc[i][c]);
                }
            }
        }

        // ---- distances + running argmin (ascending k) ----
#pragma unroll
        for (int c = 0; c < 8; ++c) {
            const int k = ch * KC + k0 + c;
#pragma unroll
            for (int i = 0; i < 8; ++i) {
                const float dist = (xx[i] - 2.f * acc[i][c]) + ee[c];
                if (dist < best[i]) { best[i] = dist; bestk[i] = k; }
            }
        }
    }

    // ---- cross-thread argmin reduce over the 16 tc groups ----
    __syncthreads();                   // all sE reads done; overlay safe
#pragma unroll
    for (int i = 0; i < 8; ++i) {
        sRbest[(v0 + i) * 17 + tc] = best[i];
        sRk   [(v0 + i) * 17 + tc] = bestk[i];
    }
    __syncthreads();

    if (t < VPB) {
        float b = sRbest[t * 17];
        int  bk = sRk[t * 17];
#pragma unroll
        for (int j = 1; j < 16; ++j) {
            const float bj = sRbest[t * 17 + j];
            const int   kj = sRk[t * 17 + j];
            if (bj < b || (bj == b && kj < bk)) { b = bj; bk = kj; }
        }
        sBK[t] = bk;
        idx[vecbase + t] = bk;
        atomicAdd(&counts[bk], 1.0f);
    }
    __syncthreads();

    // ---- full one-hot rows: 128 rows x 512 f32, coalesced float2 stores ----
    // (enc base is only 8B-aligned: out + 8388610)
    {
        const int c0 = 2 * t, c1 = 2 * t + 1;
        float* rowp = enc + vecbase * K_CODES + c0;
#pragma unroll 4
        for (int v = 0; v < VPB; ++v) {
            const int bk = sBK[v];
            float2 val;
            val.x = (c0 == bk) ? 1.0f : 0.0f;
            val.y = (c1 == bk) ? 1.0f : 0.0f;
            *reinterpret_cast<float2*>(rowp) = val;
            rowp += K_CODES;
        }
    }

    // ---- dw segment-sum: one contiguous 64-float row per wave-instruction ----
    {
        const int d  = t & 63;
        const int vp = t >> 6;         // wave-uniform
#pragma unroll
        for (int p = 0; p < 32; ++p) {
            const int v = p * 4 + vp;
            const float xval = reinterpret_cast<const float*>(sX)
                [(v * 16 + ((d >> 2) ^ (v >> 3))) * 4 + (d & 3)];
            atomicAdd(&dw[(size_t)sBK[v] * DIM + d], xval);
        }
    }
}

// ---------------------------------------------------------------------------
// Kernel 2: EMA cluster-size + Laplace smoothing + codebook update +
// perplexity. One block of K=512 threads.
// ---------------------------------------------------------------------------
__global__ __launch_bounds__(512) void ema_update_kernel(
    const float* __restrict__ counts,
    const float* __restrict__ ema_cs,
    const float* __restrict__ ema_w,
    const float* __restrict__ dw,
    float* __restrict__ new_emb,
    float* __restrict__ perp_out)
{
    __shared__ float red[K_CODES];
    const int k = threadIdx.x;

    const float cnt = counts[k];
    float cs = ema_cs[k] * 0.99f + 0.01f * cnt;

    red[k] = cs;
    __syncthreads();
    for (int s = K_CODES / 2; s > 0; s >>= 1) {
        if (k < s) red[k] += red[k + s];
        __syncthreads();
    }
    const float n = red[0];
    __syncthreads();

    cs = (cs + 1e-5f) / (n + (float)K_CODES * 1e-5f) * n;

    for (int d = 0; d < DIM; ++d) {
        const float v = ema_w[k * DIM + d] * 0.99f + 0.01f * dw[k * DIM + d];
        new_emb[k * DIM + d] = v / cs;
    }

    const float p = cnt * (1.0f / (float)N_VEC);
    red[k] = p * logf(p + 1e-10f);
    __syncthreads();
    for (int s = K_CODES / 2; s > 0; s >>= 1) {
        if (k < s) red[k] += red[k + s];
        __syncthreads();
    }
    if (k == 0) perp_out[0] = expf(-red[0]);
}

// ---------------------------------------------------------------------------
// Kernel 3: gather quantized = new_emb[idx], straight-through qst,
// NHWC -> NCHW via LDS tile, commitment-loss partials.
// ---------------------------------------------------------------------------
__global__ __launch_bounds__(256) void quantize_kernel(
    const float* __restrict__ inputs,
    const int* __restrict__ idx,
    const float* __restrict__ new_emb,
    float* __restrict__ out_q,
    float* __restrict__ loss_accum)
{
    __shared__ int sIdx[W_SZ];
    __shared__ float tile[DIM][W_SZ + 1];
    __shared__ float wsum[4];

    const int bh = blockIdx.x;
    const int b = bh >> 6, h = bh & 63;
    const int t = threadIdx.x;

    if (t < W_SZ) sIdx[t] = idx[bh * W_SZ + t];
    __syncthreads();

    const float* inRow = inputs + (size_t)bh * W_SZ * DIM;
    const int d = t & 63;
    const int wg = t >> 6;
    float lsum = 0.f;
#pragma unroll
    for (int p = 0; p < 16; ++p) {
        const int w = wg * 16 + p;
        const float xv = inRow[w * DIM + d];
        const float qv = new_emb[sIdx[w] * DIM + d];
        const float diff = qv - xv;
        tile[d][w] = xv + diff;
        lsum = fmaf(diff, diff, lsum);
    }
    __syncthreads();

    const int w2 = t & 63;
    const int dg = t >> 6;
#pragma unroll
    for (int p = 0; p < 16; ++p) {
        const int d2 = dg * 16 + p;
        out_q[(((size_t)b * DIM + d2) * H_SZ + h) * W_SZ + w2] = tile[d2][w2];
    }

    for (int off = 32; off > 0; off >>= 1) lsum += __shfl_down(lsum, off);
    if ((t & 63) == 0) wsum[t >> 6] = lsum;
    __syncthreads();
    if (t == 0) atomicAdd(loss_accum, (wsum[0] + wsum[1]) + (wsum[2] + wsum[3]));
}

__global__ void finalize_kernel(const float* __restrict__ loss_accum,
                                float* __restrict__ out_loss)
{
    out_loss[0] = 0.25f * (loss_accum[0] / 8388608.0f);
}

// ---------------------------------------------------------------------------
extern "C" void kernel_launch(void* const* d_in, const int* in_sizes, int n_in,
                              void* d_out, int out_size, void* d_ws, size_t ws_size,
                              hipStream_t stream)
{
    const float* inputs = (const float*)d_in[0];
    const float* emb_w  = (const float*)d_in[1];
    const float* ema_cs = (const float*)d_in[2];
    const float* ema_w  = (const float*)d_in[3];
    float* out = (float*)d_out;
    float* ws  = (float*)d_ws;

    // ws layout (f32 offsets) — stays within the round-2 footprint:
    int*   idxbuf = (int*)ws;            // [0, 131072)
    float* counts = ws + 131072;         // [131072, 131584)
    float* dwbuf  = ws + 131584;         // [131584, 164352)
    float* lossac = ws + 164352;         // [164352]
    float* nemb   = ws + 164353;         // [164353, 197121)
    float* eebuf  = nemb;                // overlay: ee used only before ema
                                         // writes nemb (argmin reads, then dead)

    // one contiguous zero of counts|dw|lossac (133 KB)
    hipMemsetAsync(counts, 0, (512 + 512 * DIM + 1) * sizeof(float), stream);

    ee_kernel<<<K_CODES / 64, 64, 0, stream>>>(emb_w, eebuf);

    argmin_scatter_kernel<<<N_VEC / VPB, 256, 0, stream>>>(
        inputs, emb_w, eebuf, idxbuf, counts, dwbuf, out + ENC_OFF);

    ema_update_kernel<<<1, K_CODES, 0, stream>>>(
        counts, ema_cs, ema_w, dwbuf, nemb, out + PERP_OFF);

    quantize_kernel<<<B_SZ * H_SZ, 256, 0, stream>>>(
        inputs, idxbuf, nemb, out + Q_OFF, lossac);

    finalize_kernel<<<1, 1, 0, stream>>>(lossac, out);
}